// Round 17
// baseline (347.658 us; speedup 1.0000x reference)
//
#include <hip/hip_runtime.h>
#include <hip/hip_bf16.h>

// ---------------- problem constants ----------------
constexpr int QKV  = 768;     // 3*8*32
constexpr int Nsp  = 16384;   // 16*32*32

typedef __attribute__((ext_vector_type(8))) short short8_t;            // 8 bf16
typedef __attribute__((ext_vector_type(8))) unsigned short ushort8_t;  // 8 bf16
typedef __attribute__((ext_vector_type(4))) float f32x4;
typedef __attribute__((ext_vector_type(2))) float f32x2;

__device__ inline unsigned short f2b(float f) {
    union { __hip_bfloat16 h; unsigned short u; } c;
    c.h = __float2bfloat16(f);
    return c.u;
}
__device__ inline float b2f(unsigned short u) {   // exact: bf16 -> f32 is a shift
    unsigned v = (unsigned)u << 16;
    float f;
    __builtin_memcpy(&f, &v, 4);
    return f;
}
__device__ inline ushort4 f2b4(float4 v) {
    return make_ushort4(f2b(v.x), f2b(v.y), f2b(v.z), f2b(v.w));
}

// =====================================================================
// Elementwise f32 -> bf16 (for w_qkv). n4 = elements/4.
// =====================================================================
__global__ __launch_bounds__(256)
void cvt_bf16(const float* __restrict__ in, unsigned short* __restrict__ out, int n4)
{
    int i = blockIdx.x * 256 + threadIdx.x;
    if (i < n4) {
        float4 v = reinterpret_cast<const float4*>(in)[i];
        reinterpret_cast<ushort4*>(out)[i] = f2b4(v);
    }
}

// =====================================================================
// Tiled transpose f32 [C][N] -> bf16 [N][C] (for x only).
// =====================================================================
__global__ __launch_bounds__(256)
void transposeX(const float* __restrict__ in, unsigned short* __restrict__ out)
{
    const int n0 = blockIdx.x * 64;
    const int c0 = blockIdx.y * 64;
    const int b  = blockIdx.z;
    const float* inb = in + (size_t)b * 256 * Nsp;

    __shared__ float tl[64][66];
    const int t = threadIdx.x;

#pragma unroll
    for (int r = 0; r < 8; r++) {
        int id = t + 256 * r;      // 0..2047
        int c  = id >> 5;          // 0..63
        int nh = id & 31;          // n-pair
        float2 v = *reinterpret_cast<const float2*>(
            inb + (size_t)(c0 + c) * Nsp + n0 + nh * 2);
        tl[nh * 2 + 0][c] = v.x;
        tl[nh * 2 + 1][c] = v.y;
    }
    __syncthreads();

#pragma unroll
    for (int r = 0; r < 2; r++) {
        int id = t + 256 * r;      // 0..511
        int n  = id >> 3;          // 0..63
        int cq = id & 7;
        ushort4 lo = make_ushort4(f2b(tl[n][cq*8+0]), f2b(tl[n][cq*8+1]),
                                  f2b(tl[n][cq*8+2]), f2b(tl[n][cq*8+3]));
        ushort4 hi = make_ushort4(f2b(tl[n][cq*8+4]), f2b(tl[n][cq*8+5]),
                                  f2b(tl[n][cq*8+6]), f2b(tl[n][cq*8+7]));
        unsigned short* p = out + ((size_t)b * Nsp + n0 + n) * 256 + c0 + cq * 8;
        *reinterpret_cast<ushort4*>(p)     = lo;
        *reinterpret_cast<ushort4*>(p + 4) = hi;
    }
}

// =====================================================================
// Fused q~ transpose: bf16 [heads][N] -> bf16 [N][512] with IN-TILE rden.
// =====================================================================
__global__ __launch_bounds__(256)
void transposeQT(const unsigned short* __restrict__ QKVb,
                 const unsigned short* __restrict__ AGG2,
                 const float* __restrict__ vk,      // [32][1056]
                 unsigned short* __restrict__ out)  // [2][16384][512]
{
    const int n0   = blockIdx.x * 64;
    const int yy   = blockIdx.y;          // 0..7
    const int b    = blockIdx.z;
    const int half = yy >> 2;             // 0: qkv, 1: agg2
    const int c0   = half * 256 + (yy & 3) * 64;
    const unsigned short* src = half ? AGG2 : QKVb;
    const int hA = c0 >> 5;               // first head in tile (global 0..15)

    __shared__ float tl[64][66];
    __shared__ float vkl[2][32];
    __shared__ float rdl[64][2];
    const int t = threadIdx.x;

    // stage relu(q) tile
#pragma unroll
    for (int r = 0; r < 8; r++) {
        int id = t + 256 * r;      // 0..2047
        int c  = id >> 5;          // 0..63
        int nh = id & 31;          // n-pair
        int cg = c0 + c;
        int inRow = ((cg >> 5) - (half ? 8 : 0)) * 96 + (cg & 31);
        ushort2 u = *reinterpret_cast<const ushort2*>(
            src + ((size_t)b * QKV + inRow) * Nsp + n0 + nh * 2);
        tl[nh * 2 + 0][c] = fmaxf(b2f(u.x), 0.f);
        tl[nh * 2 + 1][c] = fmaxf(b2f(u.y), 0.f);
    }
    // stage vk ones-row (vk1) for the tile's 2 heads
    if (t < 64) {
        int hh = t >> 5, j = t & 31;
        vkl[hh][j] = vk[(size_t)(b * 16 + hA + hh) * 1056 + 1024 + j];
    }
    __syncthreads();

    // denominators: 128 threads, one (n, head) pair each
    if (t < 128) {
        int n = t >> 1, hh = t & 1;
        float den = 0.f;
#pragma unroll
        for (int d = 0; d < 32; d++)
            den = fmaf(vkl[hh][d], tl[n][hh * 32 + d], den);
        rdl[n][hh] = 1.0f / (den + 1e-15f);
    }
    __syncthreads();

    // output: q~ = relu(q) * rden
#pragma unroll
    for (int r = 0; r < 2; r++) {
        int id = t + 256 * r;      // 0..511
        int n  = id >> 3;          // 0..63
        int cq = id & 7;
        float sc = rdl[n][cq >> 2];
        ushort4 lo = make_ushort4(f2b(tl[n][cq*8+0] * sc), f2b(tl[n][cq*8+1] * sc),
                                  f2b(tl[n][cq*8+2] * sc), f2b(tl[n][cq*8+3] * sc));
        ushort4 hi = make_ushort4(f2b(tl[n][cq*8+4] * sc), f2b(tl[n][cq*8+5] * sc),
                                  f2b(tl[n][cq*8+6] * sc), f2b(tl[n][cq*8+7] * sc));
        unsigned short* p = out + ((size_t)b * Nsp + n0 + n) * 512 + c0 + cq * 8;
        *reinterpret_cast<ushort4*>(p)     = lo;
        *reinterpret_cast<ushort4*>(p + 4) = hi;
    }
}

// =====================================================================
// bf16 MFMA GEMM: Y[b][co][n] = A[co][k] x B^T[n][k], K-chunks of 32.
// 128x128 tile, 4 waves (2co x 2n), each 4x4 frags of 16x16x32.
// Staging via global_load_lds width=16 into unpadded [128][32] tiles.
// =====================================================================
template<bool FUSE_BN, bool OUT_BF16>
__global__ __launch_bounds__(256)
void mfma_gemm(const unsigned short* __restrict__ A,
               const unsigned short* __restrict__ B,
               void* __restrict__ Yv, int K, int M, size_t aBStride,
               const float* __restrict__ gamma, const float* __restrict__ beta,
               const float* __restrict__ rmean, const float* __restrict__ rvar)
{
    const int n0  = blockIdx.x * 128;
    const int co0 = blockIdx.y * 128;
    const int bz  = blockIdx.z;
    const int t   = threadIdx.x;

    __shared__ __align__(16) unsigned short a_lds[128][32];
    __shared__ __align__(16) unsigned short b_lds[128][32];

    const unsigned short* Ab = A + (size_t)bz * aBStride + (size_t)co0 * K;
    const unsigned short* Bb = B + ((size_t)bz * Nsp + n0) * K;

    const int lane = t & 63;
    const int wv   = t >> 6;
    const int wco  = wv >> 1;        // 0..1
    const int wn   = wv & 1;         // 0..1
    const int lr   = lane & 15;      // fragment row/col
    const int lg   = lane >> 4;      // k-group 0..3

    f32x4 acc[4][4];
#pragma unroll
    for (int m = 0; m < 4; m++)
#pragma unroll
        for (int f = 0; f < 4; f++) acc[m][f] = (f32x4){0.f, 0.f, 0.f, 0.f};

    for (int k0 = 0; k0 < K; k0 += 32) {
        __syncthreads();
#pragma unroll
        for (int r = 0; r < 2; r++) {
            int id  = t + 256 * r;   // 0..511 ; LDS byte offset = id*16
            int row = id >> 2;       // 0..127
            int kq  = id & 3;        // 16B quad within 64B row
            __builtin_amdgcn_global_load_lds(
                (const __attribute__((address_space(1))) void*)
                    (Ab + (size_t)row * K + k0 + kq * 8),
                (__attribute__((address_space(3))) void*)&a_lds[row][kq * 8],
                16, 0, 0);
            __builtin_amdgcn_global_load_lds(
                (const __attribute__((address_space(1))) void*)
                    (Bb + (size_t)row * K + k0 + kq * 8),
                (__attribute__((address_space(3))) void*)&b_lds[row][kq * 8],
                16, 0, 0);
        }
        __syncthreads();   // compiler emits s_waitcnt vmcnt(0) before barrier

        short8_t af[4], bf[4];
#pragma unroll
        for (int m = 0; m < 4; m++)
            af[m] = *reinterpret_cast<const short8_t*>(&a_lds[wco * 64 + m * 16 + lr][lg * 8]);
#pragma unroll
        for (int f = 0; f < 4; f++)
            bf[f] = *reinterpret_cast<const short8_t*>(&b_lds[wn * 64 + f * 16 + lr][lg * 8]);
#pragma unroll
        for (int m = 0; m < 4; m++)
#pragma unroll
            for (int f = 0; f < 4; f++)
                acc[m][f] = __builtin_amdgcn_mfma_f32_16x16x32_bf16(
                    af[m], bf[f], acc[m][f], 0, 0, 0);
    }

    // epilogue: C row = co0+wco*64+m*16+4*lg+j, col = n0+wn*64+f*16+lr
#pragma unroll
    for (int m = 0; m < 4; m++) {
#pragma unroll
        for (int j = 0; j < 4; j++) {
            int co = co0 + wco * 64 + m * 16 + 4 * lg + j;
            float sc = 1.f, sh = 0.f;
            if (FUSE_BN) {
                float rs = rsqrtf(rvar[co] + 1e-5f);
                sc = gamma[co] * rs;
                sh = beta[co] - rmean[co] * sc;
            }
            if (OUT_BF16) {
                unsigned short* yp = (unsigned short*)Yv +
                    ((size_t)bz * M + co) * Nsp + n0 + wn * 64 + lr;
#pragma unroll
                for (int f = 0; f < 4; f++) yp[f * 16] = f2b(acc[m][f][j]);
            } else {
                float* yp = (float*)Yv +
                    ((size_t)bz * M + co) * Nsp + n0 + wn * 64 + lr;
#pragma unroll
                for (int f = 0; f < 4; f++) {
                    float v = acc[m][f][j];
                    yp[f * 16] = FUSE_BN ? fmaf(v, sc, sh) : v;
                }
            }
        }
    }
}

// =====================================================================
// Depthwise 5x5x5 conv — pk-fp32 inner loop (R15: 130 us, VGPR 52),
// now with 2-PLANE STEPS on a 4-buffer LDS ring: 8 barriers instead of
// 16, ~500 pk-FMA of independent work per barrier for latency hiding.
// BODY sequence (gates/rotation/outputs) identical to the proven code.
// (Scalar weights only: both VGPR-forcing attempts spilled; NEVER redo.)
// =====================================================================
#define PKFMA(AL, AH, WV, PL, PH)                      \
    { f32x2 w2_ = {WV, WV};                            \
      AL = __builtin_elementwise_fma(PL, w2_, AL);     \
      AH = __builtin_elementwise_fma(PH, w2_, AH); }

// one plane's contribution from buffer (Z&3); outputs plane Z-2 if DOWRITE
#define BODY(Z, G0, G1, G2, G3, G4, DOWRITE)                                  \
  {                                                                           \
    const int zz = (Z);                                                       \
    _Pragma("unroll")                                                         \
    for (int kh = 0; kh < 5; kh++) {                                          \
      const float* rp = &pl[zz & 3][hrow + kh][w4];                           \
      float4 c0 = *reinterpret_cast<const float4*>(rp);                       \
      float4 c1 = *reinterpret_cast<const float4*>(rp + 4);                   \
      f32x2 plo_[5], phi_[5];                                                 \
      plo_[0] = (f32x2){c0.x, c0.y};                                          \
      plo_[1] = (f32x2){c0.y, c0.z};                                          \
      plo_[2] = (f32x2){c0.z, c0.w};                                          \
      plo_[3] = (f32x2){c0.w, c1.x};                                          \
      plo_[4] = (f32x2){c1.x, c1.y};                                          \
      phi_[0] = plo_[2];                                                      \
      phi_[1] = plo_[3];                                                      \
      phi_[2] = plo_[4];                                                      \
      phi_[3] = (f32x2){c1.y, c1.z};                                          \
      phi_[4] = (f32x2){c1.z, c1.w};                                          \
      _Pragma("unroll")                                                       \
      for (int kw = 0; kw < 5; kw++) {                                        \
        if (G0) { float wv = wr[  0 + kh * 5 + kw];                           \
                  PKFMA(a0l, a0h, wv, plo_[kw], phi_[kw]) }                   \
        if (G1) { float wv = wr[ 25 + kh * 5 + kw];                           \
                  PKFMA(a1l, a1h, wv, plo_[kw], phi_[kw]) }                   \
        if (G2) { float wv = wr[ 50 + kh * 5 + kw];                           \
                  PKFMA(a2l, a2h, wv, plo_[kw], phi_[kw]) }                   \
        if (G3) { float wv = wr[ 75 + kh * 5 + kw];                           \
                  PKFMA(a3l, a3h, wv, plo_[kw], phi_[kw]) }                   \
        if (G4) { float wv = wr[100 + kh * 5 + kw];                           \
                  PKFMA(a4l, a4h, wv, plo_[kw], phi_[kw]) }                   \
      }                                                                       \
    }                                                                         \
    if (DOWRITE)                                                              \
      *reinterpret_cast<ushort4*>(Yc + ((zz - 2) * 32 + hrow) * 32 + w4)      \
          = make_ushort4(f2b(a4l.x), f2b(a4l.y), f2b(a4h.x), f2b(a4h.y));     \
    a4l = a3l; a4h = a3h; a3l = a2l; a3h = a2h;                               \
    a2l = a1l; a2h = a1h; a1l = a0l; a1h = a0h;                               \
    a0l = (f32x2){0.f, 0.f}; a0h = (f32x2){0.f, 0.f};                         \
  }

#define STAGE_WR(P, GU)                                                       \
    { pl[(P) & 3][hrow + 2][2 + w4 + 0] = b2f(GU.x);                          \
      pl[(P) & 3][hrow + 2][2 + w4 + 1] = b2f(GU.y);                          \
      pl[(P) & 3][hrow + 2][2 + w4 + 2] = b2f(GU.z);                          \
      pl[(P) & 3][hrow + 2][2 + w4 + 3] = b2f(GU.w); }

// two planes per barrier; stages planes Z+2, Z+3 when DOSTAGE
#define STEP2(Z, g00,g01,g02,g03,g04, g10,g11,g12,g13,g14, DW0, DW1, DOSTAGE) \
  {                                                                           \
    __syncthreads();                                                          \
    ushort4 gu2 = make_ushort4(0,0,0,0), gu3 = make_ushort4(0,0,0,0);         \
    if (DOSTAGE) {                                                            \
      gu2 = *reinterpret_cast<const ushort4*>(Xc + ((Z) + 2) * 1024 +         \
                                              hrow * 32 + w4);                \
      gu3 = *reinterpret_cast<const ushort4*>(Xc + ((Z) + 3) * 1024 +         \
                                              hrow * 32 + w4);                \
    }                                                                         \
    BODY((Z),     g00, g01, g02, g03, g04, DW0)                               \
    BODY((Z) + 1, g10, g11, g12, g13, g14, DW1)                               \
    if (DOSTAGE) { STAGE_WR((Z) + 2, gu2) STAGE_WR((Z) + 3, gu3) }            \
  }

__global__ __launch_bounds__(256)
void dwconv5(const unsigned short* __restrict__ X, const float* __restrict__ Wd,
             unsigned short* __restrict__ Y)
{
    const int ch = blockIdx.x;      // 0..767
    const int b  = blockIdx.y;      // 0..1
    const int t  = threadIdx.x;

    __shared__ float pl[4][36][40]; // 23 KB ring; halo permanently zero

    const unsigned short* Xc = X + ((size_t)b * QKV + ch) * Nsp;
    unsigned short*       Yc = Y + ((size_t)b * QKV + ch) * Nsp;
    const float* wp = Wd + ch * 125;

    float wr[125];
#pragma unroll
    for (int i = 0; i < 125; i++) wr[i] = wp[i];

    for (int i = t; i < 4 * 36 * 40; i += 256)
        (&pl[0][0][0])[i] = 0.f;

    const int hrow = t >> 3;
    const int w4   = (t & 7) * 4;

    __syncthreads();                // zeros visible before staging 0,1
    {
        ushort4 g0 = *reinterpret_cast<const ushort4*>(Xc + hrow * 32 + w4);
        ushort4 g1 = *reinterpret_cast<const ushort4*>(Xc + 1024 + hrow * 32 + w4);
        STAGE_WR(0, g0)
        STAGE_WR(1, g1)
    }

    f32x2 a0l = {0,0}, a0h = a0l, a1l = a0l, a1h = a0l, a2l = a0l,
          a2h = a0l, a3l = a0l, a3h = a0l, a4l = a0l, a4h = a0l;

    // step (0,1): gates z=0:(T,T,T,F,F)  z=1:(T,T,T,T,F); no outputs yet
    STEP2(0, true,true,true,false,false,  true,true,true,true,false,
          false, false, true)
    // steps (2,3)..(12,13): full gates, outputs z-2, z-1; stage z+2, z+3
#pragma unroll 1
    for (int z = 2; z <= 12; z += 2) {
        STEP2(z, true,true,true,true,true,  true,true,true,true,true,
              true, true, true)
    }
    // step (14,15): gates z=14:(F,T,T,T,T)  z=15:(F,F,T,T,T); no staging
    STEP2(14, false,true,true,true,true,  false,false,true,true,true,
          true, true, false)
    // after BODY(15) rotation: a4 = plane 14, a3 = plane 15
    *reinterpret_cast<ushort4*>(Yc + ((14 * 32 + hrow) * 32 + w4))
        = make_ushort4(f2b(a4l.x), f2b(a4l.y), f2b(a4h.x), f2b(a4h.y));
    *reinterpret_cast<ushort4*>(Yc + ((15 * 32 + hrow) * 32 + w4))
        = make_ushort4(f2b(a3l.x), f2b(a3l.y), f2b(a3h.x), f2b(a3h.y));
}

// =====================================================================
// Grouped pointwise conv, both batches: bf16 in, bf16 out.
// =====================================================================
__global__ __launch_bounds__(256)
void pwconv(const unsigned short* __restrict__ X, const float* __restrict__ Wp,
            unsigned short* __restrict__ Y)
{
    const int n0 = blockIdx.x * 256;
    const int g  = blockIdx.y;      // 0..23
    const int bz = blockIdx.z;
    const int t  = threadIdx.x;
    const int lane = t & 63, wv = t >> 6;

    __shared__ float xs[32][256];

    const unsigned short* Xg = X + ((size_t)bz * QKV + g * 32) * Nsp + n0;
#pragma unroll
    for (int rr = 0; rr < 8; rr++) {
        int r = wv + rr * 4;
        ushort4 u = *reinterpret_cast<const ushort4*>(Xg + (size_t)r * Nsp + lane * 4);
        xs[r][lane * 4 + 0] = b2f(u.x);
        xs[r][lane * 4 + 1] = b2f(u.y);
        xs[r][lane * 4 + 2] = b2f(u.z);
        xs[r][lane * 4 + 3] = b2f(u.w);
    }
    __syncthreads();

    float xin[32];
#pragma unroll
    for (int j = 0; j < 32; j++) xin[j] = xs[j][t];

    const float* wg = Wp + g * 1024;
    unsigned short* Yg = Y + ((size_t)bz * QKV + g * 32) * Nsp + n0;
#pragma unroll 4
    for (int co = 0; co < 32; co++) {
        float acc = 0;
#pragma unroll
        for (int j = 0; j < 32; j++) acc = fmaf(wg[co * 32 + j], xin[j], acc);
        Yg[(size_t)co * Nsp + t] = f2b(acc);
    }
}

// =====================================================================
// Attention phase 1: vk[e][d] partials, 16 chunks x 1024 n each.
// =====================================================================
__global__ __launch_bounds__(256)
void att_vk(const unsigned short* __restrict__ QKVb,
            const unsigned short* __restrict__ AGG2,
            float* __restrict__ vk_part)
{
    const int chunk = blockIdx.x;   // 0..15
    const int bh    = blockIdx.y;   // 0..31
    const int b = bh >> 4, head = bh & 15;
    const unsigned short* base = (head < 8)
        ? QKVb + ((size_t)b * QKV + head * 96) * Nsp
        : AGG2 + ((size_t)b * QKV + (head - 8) * 96) * Nsp;

    __shared__ float ks[32][256];
    __shared__ float vs[32][256];

    const int t = threadIdx.x;
    const int a  = t & 15;
    const int e0 = t >> 4;          // 0..15
    const int d0 = 2 * a;
    const int rot = (2 * d0 + 34 * e0) & 255;

    float a00 = 0, a01 = 0, a10 = 0, a11 = 0, s0 = 0, s1 = 0;

    for (int sub = 0; sub < 4; sub++) {
        const int n0 = chunk * 1024 + sub * 256;
        __syncthreads();
#pragma unroll
        for (int rr = 0; rr < 8; rr++) {
            int id  = t + 256 * rr;     // 0..2047
            int rid = id >> 5;          // 0..63: k rows 0-31, v rows 32-63
            int cg  = id & 31;          // 8-col group
            ushort8_t u = *reinterpret_cast<const ushort8_t*>(
                base + (size_t)(32 + rid) * Nsp + n0 + cg * 8);
            float f[8];
#pragma unroll
            for (int j = 0; j < 8; j++) f[j] = b2f(u[j]);
            if (rid < 32) {
#pragma unroll
                for (int j = 0; j < 8; j++) ks[rid][cg * 8 + j] = fmaxf(f[j], 0.f);
            } else {
#pragma unroll
                for (int j = 0; j < 8; j++) vs[rid - 32][cg * 8 + j] = f[j];
            }
        }
        __syncthreads();

#pragma unroll 4
        for (int n = 0; n < 256; n += 2) {
            int nn = (n + rot) & 255;
            float2 k0 = *reinterpret_cast<const float2*>(&ks[d0][nn]);
            float2 k1 = *reinterpret_cast<const float2*>(&ks[d0 + 1][nn]);
            float2 v0 = *reinterpret_cast<const float2*>(&vs[e0][nn]);
            float2 v1 = *reinterpret_cast<const float2*>(&vs[e0 + 16][nn]);
            a00 = fmaf(v0.x, k0.x, fmaf(v0.y, k0.y, a00));
            a01 = fmaf(v0.x, k1.x, fmaf(v0.y, k1.y, a01));
            a10 = fmaf(v1.x, k0.x, fmaf(v1.y, k0.y, a10));
            a11 = fmaf(v1.x, k1.x, fmaf(v1.y, k1.y, a11));
            s0 += k0.x + k0.y;
            s1 += k1.x + k1.y;
        }
    }

    float* vp = vk_part + ((size_t)bh * 16 + chunk) * 1056;
    vp[e0 * 32 + d0]            = a00;
    vp[e0 * 32 + d0 + 1]        = a01;
    vp[(e0 + 16) * 32 + d0]     = a10;
    vp[(e0 + 16) * 32 + d0 + 1] = a11;
    if (e0 == 0) {
        vp[32 * 32 + d0]     = s0;
        vp[32 * 32 + d0 + 1] = s1;
    }
}

// Reduce the 16 chunk partials -> vk[bh][33][32]
__global__ __launch_bounds__(256)
void att_vk_reduce(const float* __restrict__ vk_part, float* __restrict__ vk)
{
    const int bh = blockIdx.x;
    const int t  = threadIdx.x;
    for (int id = t; id < 1056; id += 256) {
        const float* p = vk_part + (size_t)bh * 16 * 1056 + id;
        float s = 0;
#pragma unroll
        for (int c = 0; c < 16; c++) s += p[(size_t)c * 1056];
        vk[bh * 1056 + id] = s;
    }
}

// =====================================================================
// M'[b][co][h*32+d] = sum_e w_proj[co][h*32+e] * vk[b*16+h][e][d]  (bf16 out)
// =====================================================================
__global__ __launch_bounds__(256)
void mprep(const float* __restrict__ Wproj, const float* __restrict__ vk,
           unsigned short* __restrict__ Mp)
{
    const int b   = blockIdx.y;
    const int co0 = blockIdx.x * 16;
    const int t   = threadIdx.x;
    for (int ci = 0; ci < 16; ci++) {
        int co = co0 + ci;
        for (int hd = t; hd < 512; hd += 256) {
            int h = hd >> 5, d = hd & 31;
            const float* wrow = Wproj + (size_t)co * 512 + h * 32;
            const float* vkb  = vk + (size_t)(b * 16 + h) * 1056 + d;
            float s = 0;
#pragma unroll
            for (int e = 0; e < 32; e++) s = fmaf(wrow[e], vkb[e * 32], s);
            Mp[((size_t)b * 256 + co) * 512 + hd] = f2b(s);
        }
    }
}

// =====================================================================
extern "C" void kernel_launch(void* const* d_in, const int* in_sizes, int n_in,
                              void* d_out, int out_size, void* d_ws, size_t ws_size,
                              hipStream_t stream)
{
    const float* x      = (const float*)d_in[0];
    const float* w_qkv  = (const float*)d_in[1];
    const float* w_dw   = (const float*)d_in[2];
    const float* w_pw   = (const float*)d_in[3];
    const float* w_proj = (const float*)d_in[4];
    const float* gamma  = (const float*)d_in[5];
    const float* beta   = (const float*)d_in[6];
    const float* rmean  = (const float*)d_in[7];
    const float* rvar   = (const float*)d_in[8];
    float* out = (float*)d_out;

    const size_t QB = (size_t)2 * QKV * Nsp;        // elements, 2-batch tensor
    unsigned short* qkv  = (unsigned short*)d_ws;   // bf16 [2][768][16384]
    unsigned short* agg2 = qkv + QB;                // bf16 [2][768][16384]
    unsigned short* Rb   = agg2 + QB;               // time-shared 50.3 MB region:
    unsigned short* xT   = Rb;                      //  [2][16384][256]  (steps 2-3)
    unsigned short* aggH = Rb;                      //  [2][768][16384]  (steps 4-5)
    unsigned short* qT   = Rb;                      //  [2][16384][512]  (steps 8-9)
    float* vkp  = (float*)(Rb + QB);                // 32*16*1056
    float* vkf  = vkp + (size_t)32 * 16 * 1056;     // 32*1056
    unsigned short* Mp  = (unsigned short*)(vkf + (size_t)32 * 1056); // 2*256*512
    unsigned short* wqb = Mp + (size_t)2 * 256 * 512;                 // 768*256

    dim3 blk(256);
    // 1) w_qkv -> bf16
    cvt_bf16<<<dim3(192), blk, 0, stream>>>(w_qkv, wqb, 768 * 256 / 4);
    // 2) xT = transpose(x) bf16
    transposeX<<<dim3(256, 4, 2), blk, 0, stream>>>(x, xT);
    // 3) qkv = wqb x xT  (MFMA, bf16 out, gload_lds staging)
    mfma_gemm<false, true><<<dim3(128, 6, 2), blk, 0, stream>>>(
        wqb, xT, qkv, 256, 768, 0, nullptr, nullptr, nullptr, nullptr);
    // 4) depthwise 5^3, both batches, pk + 2-plane steps (xT dead)
    dwconv5<<<dim3(768, 2), blk, 0, stream>>>(qkv, w_dw, aggH);
    // 5) grouped pointwise, both batches
    pwconv<<<dim3(64, 24, 2), blk, 0, stream>>>(aggH, w_pw, agg2);
    // 6) vk partials + reduce
    att_vk<<<dim3(16, 32), blk, 0, stream>>>(qkv, agg2, vkp);
    att_vk_reduce<<<dim3(32), blk, 0, stream>>>(vkp, vkf);
    // 7) M' (bf16)
    mprep<<<dim3(16, 2), blk, 0, stream>>>(w_proj, vkf, Mp);
    // 8) q~T with fused in-tile rden (aggH dead)
    transposeQT<<<dim3(256, 8, 2), blk, 0, stream>>>(qkv, agg2, vkf, qT);
    // 9) out = Mp x q~T + BN  (MFMA, f32 out, gload_lds staging)
    mfma_gemm<true, false><<<dim3(128, 2, 2), blk, 0, stream>>>(
        Mp, qT, out, 512, 256, (size_t)256 * 512,
        gamma, beta, rmean, rvar);
}

// Round 18
// 328.718 us; speedup vs baseline: 1.0576x; 1.0576x over previous
//
#include <hip/hip_runtime.h>
#include <hip/hip_bf16.h>

// ---------------- problem constants ----------------
constexpr int QKV  = 768;     // 3*8*32
constexpr int Nsp  = 16384;   // 16*32*32

typedef __attribute__((ext_vector_type(8))) short short8_t;            // 8 bf16
typedef __attribute__((ext_vector_type(8))) unsigned short ushort8_t;  // 8 bf16
typedef __attribute__((ext_vector_type(4))) float f32x4;
typedef __attribute__((ext_vector_type(2))) float f32x2;

__device__ inline unsigned short f2b(float f) {
    union { __hip_bfloat16 h; unsigned short u; } c;
    c.h = __float2bfloat16(f);
    return c.u;
}
__device__ inline float b2f(unsigned short u) {   // exact: bf16 -> f32 is a shift
    unsigned v = (unsigned)u << 16;
    float f;
    __builtin_memcpy(&f, &v, 4);
    return f;
}
__device__ inline ushort4 f2b4(float4 v) {
    return make_ushort4(f2b(v.x), f2b(v.y), f2b(v.z), f2b(v.w));
}

// =====================================================================
// Elementwise f32 -> bf16 (for w_qkv). n4 = elements/4.
// =====================================================================
__global__ __launch_bounds__(256)
void cvt_bf16(const float* __restrict__ in, unsigned short* __restrict__ out, int n4)
{
    int i = blockIdx.x * 256 + threadIdx.x;
    if (i < n4) {
        float4 v = reinterpret_cast<const float4*>(in)[i];
        reinterpret_cast<ushort4*>(out)[i] = f2b4(v);
    }
}

// =====================================================================
// Tiled transpose f32 [C][N] -> bf16 [N][C] (for x only).
// =====================================================================
__global__ __launch_bounds__(256)
void transposeX(const float* __restrict__ in, unsigned short* __restrict__ out)
{
    const int n0 = blockIdx.x * 64;
    const int c0 = blockIdx.y * 64;
    const int b  = blockIdx.z;
    const float* inb = in + (size_t)b * 256 * Nsp;

    __shared__ float tl[64][66];
    const int t = threadIdx.x;

#pragma unroll
    for (int r = 0; r < 8; r++) {
        int id = t + 256 * r;      // 0..2047
        int c  = id >> 5;          // 0..63
        int nh = id & 31;          // n-pair
        float2 v = *reinterpret_cast<const float2*>(
            inb + (size_t)(c0 + c) * Nsp + n0 + nh * 2);
        tl[nh * 2 + 0][c] = v.x;
        tl[nh * 2 + 1][c] = v.y;
    }
    __syncthreads();

#pragma unroll
    for (int r = 0; r < 2; r++) {
        int id = t + 256 * r;      // 0..511
        int n  = id >> 3;          // 0..63
        int cq = id & 7;
        ushort4 lo = make_ushort4(f2b(tl[n][cq*8+0]), f2b(tl[n][cq*8+1]),
                                  f2b(tl[n][cq*8+2]), f2b(tl[n][cq*8+3]));
        ushort4 hi = make_ushort4(f2b(tl[n][cq*8+4]), f2b(tl[n][cq*8+5]),
                                  f2b(tl[n][cq*8+6]), f2b(tl[n][cq*8+7]));
        unsigned short* p = out + ((size_t)b * Nsp + n0 + n) * 256 + c0 + cq * 8;
        *reinterpret_cast<ushort4*>(p)     = lo;
        *reinterpret_cast<ushort4*>(p + 4) = hi;
    }
}

// =====================================================================
// Fused q~ transpose: bf16 [heads][N] -> bf16 [N][512] with IN-TILE rden.
// =====================================================================
__global__ __launch_bounds__(256)
void transposeQT(const unsigned short* __restrict__ QKVb,
                 const unsigned short* __restrict__ AGG2,
                 const float* __restrict__ vk,      // [32][1056]
                 unsigned short* __restrict__ out)  // [2][16384][512]
{
    const int n0   = blockIdx.x * 64;
    const int yy   = blockIdx.y;          // 0..7
    const int b    = blockIdx.z;
    const int half = yy >> 2;             // 0: qkv, 1: agg2
    const int c0   = half * 256 + (yy & 3) * 64;
    const unsigned short* src = half ? AGG2 : QKVb;
    const int hA = c0 >> 5;               // first head in tile (global 0..15)

    __shared__ float tl[64][66];
    __shared__ float vkl[2][32];
    __shared__ float rdl[64][2];
    const int t = threadIdx.x;

    // stage relu(q) tile
#pragma unroll
    for (int r = 0; r < 8; r++) {
        int id = t + 256 * r;      // 0..2047
        int c  = id >> 5;          // 0..63
        int nh = id & 31;          // n-pair
        int cg = c0 + c;
        int inRow = ((cg >> 5) - (half ? 8 : 0)) * 96 + (cg & 31);
        ushort2 u = *reinterpret_cast<const ushort2*>(
            src + ((size_t)b * QKV + inRow) * Nsp + n0 + nh * 2);
        tl[nh * 2 + 0][c] = fmaxf(b2f(u.x), 0.f);
        tl[nh * 2 + 1][c] = fmaxf(b2f(u.y), 0.f);
    }
    // stage vk ones-row (vk1) for the tile's 2 heads
    if (t < 64) {
        int hh = t >> 5, j = t & 31;
        vkl[hh][j] = vk[(size_t)(b * 16 + hA + hh) * 1056 + 1024 + j];
    }
    __syncthreads();

    // denominators: 128 threads, one (n, head) pair each
    if (t < 128) {
        int n = t >> 1, hh = t & 1;
        float den = 0.f;
#pragma unroll
        for (int d = 0; d < 32; d++)
            den = fmaf(vkl[hh][d], tl[n][hh * 32 + d], den);
        rdl[n][hh] = 1.0f / (den + 1e-15f);
    }
    __syncthreads();

    // output: q~ = relu(q) * rden
#pragma unroll
    for (int r = 0; r < 2; r++) {
        int id = t + 256 * r;      // 0..511
        int n  = id >> 3;          // 0..63
        int cq = id & 7;
        float sc = rdl[n][cq >> 2];
        ushort4 lo = make_ushort4(f2b(tl[n][cq*8+0] * sc), f2b(tl[n][cq*8+1] * sc),
                                  f2b(tl[n][cq*8+2] * sc), f2b(tl[n][cq*8+3] * sc));
        ushort4 hi = make_ushort4(f2b(tl[n][cq*8+4] * sc), f2b(tl[n][cq*8+5] * sc),
                                  f2b(tl[n][cq*8+6] * sc), f2b(tl[n][cq*8+7] * sc));
        unsigned short* p = out + ((size_t)b * Nsp + n0 + n) * 512 + c0 + cq * 8;
        *reinterpret_cast<ushort4*>(p)     = lo;
        *reinterpret_cast<ushort4*>(p + 4) = hi;
    }
}

// =====================================================================
// bf16 MFMA GEMM: Y[b][co][n] = A[co][k] x B^T[n][k], K-chunks of 32.
// 128x128 tile, 4 waves (2co x 2n), each 4x4 frags of 16x16x32.
// Staging via global_load_lds width=16 into unpadded [128][32] tiles.
// =====================================================================
template<bool FUSE_BN, bool OUT_BF16>
__global__ __launch_bounds__(256)
void mfma_gemm(const unsigned short* __restrict__ A,
               const unsigned short* __restrict__ B,
               void* __restrict__ Yv, int K, int M, size_t aBStride,
               const float* __restrict__ gamma, const float* __restrict__ beta,
               const float* __restrict__ rmean, const float* __restrict__ rvar)
{
    const int n0  = blockIdx.x * 128;
    const int co0 = blockIdx.y * 128;
    const int bz  = blockIdx.z;
    const int t   = threadIdx.x;

    __shared__ __align__(16) unsigned short a_lds[128][32];
    __shared__ __align__(16) unsigned short b_lds[128][32];

    const unsigned short* Ab = A + (size_t)bz * aBStride + (size_t)co0 * K;
    const unsigned short* Bb = B + ((size_t)bz * Nsp + n0) * K;

    const int lane = t & 63;
    const int wv   = t >> 6;
    const int wco  = wv >> 1;        // 0..1
    const int wn   = wv & 1;         // 0..1
    const int lr   = lane & 15;      // fragment row/col
    const int lg   = lane >> 4;      // k-group 0..3

    f32x4 acc[4][4];
#pragma unroll
    for (int m = 0; m < 4; m++)
#pragma unroll
        for (int f = 0; f < 4; f++) acc[m][f] = (f32x4){0.f, 0.f, 0.f, 0.f};

    for (int k0 = 0; k0 < K; k0 += 32) {
        __syncthreads();
#pragma unroll
        for (int r = 0; r < 2; r++) {
            int id  = t + 256 * r;   // 0..511 ; LDS byte offset = id*16
            int row = id >> 2;       // 0..127
            int kq  = id & 3;        // 16B quad within 64B row
            __builtin_amdgcn_global_load_lds(
                (const __attribute__((address_space(1))) void*)
                    (Ab + (size_t)row * K + k0 + kq * 8),
                (__attribute__((address_space(3))) void*)&a_lds[row][kq * 8],
                16, 0, 0);
            __builtin_amdgcn_global_load_lds(
                (const __attribute__((address_space(1))) void*)
                    (Bb + (size_t)row * K + k0 + kq * 8),
                (__attribute__((address_space(3))) void*)&b_lds[row][kq * 8],
                16, 0, 0);
        }
        __syncthreads();   // compiler emits s_waitcnt vmcnt(0) before barrier

        short8_t af[4], bf[4];
#pragma unroll
        for (int m = 0; m < 4; m++)
            af[m] = *reinterpret_cast<const short8_t*>(&a_lds[wco * 64 + m * 16 + lr][lg * 8]);
#pragma unroll
        for (int f = 0; f < 4; f++)
            bf[f] = *reinterpret_cast<const short8_t*>(&b_lds[wn * 64 + f * 16 + lr][lg * 8]);
#pragma unroll
        for (int m = 0; m < 4; m++)
#pragma unroll
            for (int f = 0; f < 4; f++)
                acc[m][f] = __builtin_amdgcn_mfma_f32_16x16x32_bf16(
                    af[m], bf[f], acc[m][f], 0, 0, 0);
    }

    // epilogue: C row = co0+wco*64+m*16+4*lg+j, col = n0+wn*64+f*16+lr
#pragma unroll
    for (int m = 0; m < 4; m++) {
#pragma unroll
        for (int j = 0; j < 4; j++) {
            int co = co0 + wco * 64 + m * 16 + 4 * lg + j;
            float sc = 1.f, sh = 0.f;
            if (FUSE_BN) {
                float rs = rsqrtf(rvar[co] + 1e-5f);
                sc = gamma[co] * rs;
                sh = beta[co] - rmean[co] * sc;
            }
            if (OUT_BF16) {
                unsigned short* yp = (unsigned short*)Yv +
                    ((size_t)bz * M + co) * Nsp + n0 + wn * 64 + lr;
#pragma unroll
                for (int f = 0; f < 4; f++) yp[f * 16] = f2b(acc[m][f][j]);
            } else {
                float* yp = (float*)Yv +
                    ((size_t)bz * M + co) * Nsp + n0 + wn * 64 + lr;
#pragma unroll
                for (int f = 0; f < 4; f++) {
                    float v = acc[m][f][j];
                    yp[f * 16] = FUSE_BN ? fmaf(v, sc, sh) : v;
                }
            }
        }
    }
}

// =====================================================================
// Depthwise 5x5x5 conv — R15 PROVEN FORM (130 us, VGPR 52, 11.5 KB LDS,
// 8 blocks/CU): pk-fp32 inner loop, 2-buffer ring, 16 plane-steps.
// Structural ledger: VGPR-forcing spilled (R7/R12); D-split lost
// (R8/R9); 2-plane/4-buffer ring lost to LDS-occupancy (R17: 6
// blocks/CU, 159 us). This is the empirical optimum — do not perturb.
// =====================================================================
#define PKFMA(AL, AH, WV, PL, PH)                      \
    { f32x2 w2_ = {WV, WV};                            \
      AL = __builtin_elementwise_fma(PL, w2_, AL);     \
      AH = __builtin_elementwise_fma(PH, w2_, AH); }

#define PLANE_STEP(Z, G0, G1, G2, G3, G4, DOWRITE, DOSTAGE)                   \
  {                                                                           \
    const int zz  = (Z);                                                      \
    const int cur = zz & 1;                                                   \
    __syncthreads();                                                          \
    ushort4 gu = make_ushort4(0, 0, 0, 0);                                    \
    if (DOSTAGE)                                                              \
      gu = *reinterpret_cast<const ushort4*>(Xc + (zz + 1) * 1024 +           \
                                             hrow * 32 + w4);                 \
    _Pragma("unroll")                                                         \
    for (int kh = 0; kh < 5; kh++) {                                          \
      const float* rp = &pl[cur][hrow + kh][w4];                              \
      float4 c0 = *reinterpret_cast<const float4*>(rp);                       \
      float4 c1 = *reinterpret_cast<const float4*>(rp + 4);                   \
      f32x2 plo_[5], phi_[5];                                                 \
      plo_[0] = (f32x2){c0.x, c0.y};                                          \
      plo_[1] = (f32x2){c0.y, c0.z};                                          \
      plo_[2] = (f32x2){c0.z, c0.w};                                          \
      plo_[3] = (f32x2){c0.w, c1.x};                                          \
      plo_[4] = (f32x2){c1.x, c1.y};                                          \
      phi_[0] = plo_[2];                                                      \
      phi_[1] = plo_[3];                                                      \
      phi_[2] = plo_[4];                                                      \
      phi_[3] = (f32x2){c1.y, c1.z};                                          \
      phi_[4] = (f32x2){c1.z, c1.w};                                          \
      _Pragma("unroll")                                                       \
      for (int kw = 0; kw < 5; kw++) {                                        \
        if (G0) { float wv = wr[  0 + kh * 5 + kw];                           \
                  PKFMA(a0l, a0h, wv, plo_[kw], phi_[kw]) }                   \
        if (G1) { float wv = wr[ 25 + kh * 5 + kw];                           \
                  PKFMA(a1l, a1h, wv, plo_[kw], phi_[kw]) }                   \
        if (G2) { float wv = wr[ 50 + kh * 5 + kw];                           \
                  PKFMA(a2l, a2h, wv, plo_[kw], phi_[kw]) }                   \
        if (G3) { float wv = wr[ 75 + kh * 5 + kw];                           \
                  PKFMA(a3l, a3h, wv, plo_[kw], phi_[kw]) }                   \
        if (G4) { float wv = wr[100 + kh * 5 + kw];                           \
                  PKFMA(a4l, a4h, wv, plo_[kw], phi_[kw]) }                   \
      }                                                                       \
    }                                                                         \
    if (DOWRITE)                                                              \
      *reinterpret_cast<ushort4*>(Yc + ((zz - 2) * 32 + hrow) * 32 + w4)      \
          = make_ushort4(f2b(a4l.x), f2b(a4l.y), f2b(a4h.x), f2b(a4h.y));     \
    a4l = a3l; a4h = a3h; a3l = a2l; a3h = a2h;                               \
    a2l = a1l; a2h = a1h; a1l = a0l; a1h = a0h;                               \
    a0l = (f32x2){0.f, 0.f}; a0h = (f32x2){0.f, 0.f};                         \
    if (DOSTAGE) {                                                            \
      const int nxt = cur ^ 1;                                                \
      pl[nxt][hrow + 2][2 + w4 + 0] = b2f(gu.x);                              \
      pl[nxt][hrow + 2][2 + w4 + 1] = b2f(gu.y);                              \
      pl[nxt][hrow + 2][2 + w4 + 2] = b2f(gu.z);                              \
      pl[nxt][hrow + 2][2 + w4 + 3] = b2f(gu.w);                              \
    }                                                                         \
  }

__global__ __launch_bounds__(256)
void dwconv5(const unsigned short* __restrict__ X, const float* __restrict__ Wd,
             unsigned short* __restrict__ Y)
{
    const int ch = blockIdx.x;      // 0..767
    const int b  = blockIdx.y;      // 0..1
    const int t  = threadIdx.x;

    __shared__ float pl[2][36][40];

    const unsigned short* Xc = X + ((size_t)b * QKV + ch) * Nsp;
    unsigned short*       Yc = Y + ((size_t)b * QKV + ch) * Nsp;
    const float* wp = Wd + ch * 125;

    float wr[125];
#pragma unroll
    for (int i = 0; i < 125; i++) wr[i] = wp[i];

    for (int i = t; i < 2 * 36 * 40; i += 256)
        (&pl[0][0][0])[i] = 0.f;

    const int hrow = t >> 3;
    const int w4   = (t & 7) * 4;

    __syncthreads();
    {
        ushort4 gu = *reinterpret_cast<const ushort4*>(Xc + hrow * 32 + w4);
        pl[0][hrow + 2][2 + w4 + 0] = b2f(gu.x);
        pl[0][hrow + 2][2 + w4 + 1] = b2f(gu.y);
        pl[0][hrow + 2][2 + w4 + 2] = b2f(gu.z);
        pl[0][hrow + 2][2 + w4 + 3] = b2f(gu.w);
    }

    f32x2 a0l = {0,0}, a0h = a0l, a1l = a0l, a1h = a0l, a2l = a0l,
          a2h = a0l, a3l = a0l, a3h = a0l, a4l = a0l, a4h = a0l;

    PLANE_STEP(0, true, true, true, false, false, false, true)
    PLANE_STEP(1, true, true, true, true,  false, false, true)
#pragma unroll 1
    for (int z = 2; z <= 13; z++) {
        PLANE_STEP(z, true, true, true, true, true, true, true)
    }
    PLANE_STEP(14, false, true,  true, true, true, true, true)
    PLANE_STEP(15, false, false, true, true, true, true, false)
    // after z=15 rotation: a4 = plane 14, a3 = plane 15
    *reinterpret_cast<ushort4*>(Yc + ((14 * 32 + hrow) * 32 + w4))
        = make_ushort4(f2b(a4l.x), f2b(a4l.y), f2b(a4h.x), f2b(a4h.y));
    *reinterpret_cast<ushort4*>(Yc + ((15 * 32 + hrow) * 32 + w4))
        = make_ushort4(f2b(a3l.x), f2b(a3l.y), f2b(a3h.x), f2b(a3h.y));
}

// =====================================================================
// Grouped pointwise conv, both batches: bf16 in, bf16 out.
// =====================================================================
__global__ __launch_bounds__(256)
void pwconv(const unsigned short* __restrict__ X, const float* __restrict__ Wp,
            unsigned short* __restrict__ Y)
{
    const int n0 = blockIdx.x * 256;
    const int g  = blockIdx.y;      // 0..23
    const int bz = blockIdx.z;
    const int t  = threadIdx.x;
    const int lane = t & 63, wv = t >> 6;

    __shared__ float xs[32][256];

    const unsigned short* Xg = X + ((size_t)bz * QKV + g * 32) * Nsp + n0;
#pragma unroll
    for (int rr = 0; rr < 8; rr++) {
        int r = wv + rr * 4;
        ushort4 u = *reinterpret_cast<const ushort4*>(Xg + (size_t)r * Nsp + lane * 4);
        xs[r][lane * 4 + 0] = b2f(u.x);
        xs[r][lane * 4 + 1] = b2f(u.y);
        xs[r][lane * 4 + 2] = b2f(u.z);
        xs[r][lane * 4 + 3] = b2f(u.w);
    }
    __syncthreads();

    float xin[32];
#pragma unroll
    for (int j = 0; j < 32; j++) xin[j] = xs[j][t];

    const float* wg = Wp + g * 1024;
    unsigned short* Yg = Y + ((size_t)bz * QKV + g * 32) * Nsp + n0;
#pragma unroll 4
    for (int co = 0; co < 32; co++) {
        float acc = 0;
#pragma unroll
        for (int j = 0; j < 32; j++) acc = fmaf(wg[co * 32 + j], xin[j], acc);
        Yg[(size_t)co * Nsp + t] = f2b(acc);
    }
}

// =====================================================================
// Attention phase 1: vk[e][d] partials, 16 chunks x 1024 n each.
// =====================================================================
__global__ __launch_bounds__(256)
void att_vk(const unsigned short* __restrict__ QKVb,
            const unsigned short* __restrict__ AGG2,
            float* __restrict__ vk_part)
{
    const int chunk = blockIdx.x;   // 0..15
    const int bh    = blockIdx.y;   // 0..31
    const int b = bh >> 4, head = bh & 15;
    const unsigned short* base = (head < 8)
        ? QKVb + ((size_t)b * QKV + head * 96) * Nsp
        : AGG2 + ((size_t)b * QKV + (head - 8) * 96) * Nsp;

    __shared__ float ks[32][256];
    __shared__ float vs[32][256];

    const int t = threadIdx.x;
    const int a  = t & 15;
    const int e0 = t >> 4;          // 0..15
    const int d0 = 2 * a;
    const int rot = (2 * d0 + 34 * e0) & 255;

    float a00 = 0, a01 = 0, a10 = 0, a11 = 0, s0 = 0, s1 = 0;

    for (int sub = 0; sub < 4; sub++) {
        const int n0 = chunk * 1024 + sub * 256;
        __syncthreads();
#pragma unroll
        for (int rr = 0; rr < 8; rr++) {
            int id  = t + 256 * rr;     // 0..2047
            int rid = id >> 5;          // 0..63: k rows 0-31, v rows 32-63
            int cg  = id & 31;          // 8-col group
            ushort8_t u = *reinterpret_cast<const ushort8_t*>(
                base + (size_t)(32 + rid) * Nsp + n0 + cg * 8);
            float f[8];
#pragma unroll
            for (int j = 0; j < 8; j++) f[j] = b2f(u[j]);
            if (rid < 32) {
#pragma unroll
                for (int j = 0; j < 8; j++) ks[rid][cg * 8 + j] = fmaxf(f[j], 0.f);
            } else {
#pragma unroll
                for (int j = 0; j < 8; j++) vs[rid - 32][cg * 8 + j] = f[j];
            }
        }
        __syncthreads();

#pragma unroll 4
        for (int n = 0; n < 256; n += 2) {
            int nn = (n + rot) & 255;
            float2 k0 = *reinterpret_cast<const float2*>(&ks[d0][nn]);
            float2 k1 = *reinterpret_cast<const float2*>(&ks[d0 + 1][nn]);
            float2 v0 = *reinterpret_cast<const float2*>(&vs[e0][nn]);
            float2 v1 = *reinterpret_cast<const float2*>(&vs[e0 + 16][nn]);
            a00 = fmaf(v0.x, k0.x, fmaf(v0.y, k0.y, a00));
            a01 = fmaf(v0.x, k1.x, fmaf(v0.y, k1.y, a01));
            a10 = fmaf(v1.x, k0.x, fmaf(v1.y, k0.y, a10));
            a11 = fmaf(v1.x, k1.x, fmaf(v1.y, k1.y, a11));
            s0 += k0.x + k0.y;
            s1 += k1.x + k1.y;
        }
    }

    float* vp = vk_part + ((size_t)bh * 16 + chunk) * 1056;
    vp[e0 * 32 + d0]            = a00;
    vp[e0 * 32 + d0 + 1]        = a01;
    vp[(e0 + 16) * 32 + d0]     = a10;
    vp[(e0 + 16) * 32 + d0 + 1] = a11;
    if (e0 == 0) {
        vp[32 * 32 + d0]     = s0;
        vp[32 * 32 + d0 + 1] = s1;
    }
}

// Reduce the 16 chunk partials -> vk[bh][33][32]
__global__ __launch_bounds__(256)
void att_vk_reduce(const float* __restrict__ vk_part, float* __restrict__ vk)
{
    const int bh = blockIdx.x;
    const int t  = threadIdx.x;
    for (int id = t; id < 1056; id += 256) {
        const float* p = vk_part + (size_t)bh * 16 * 1056 + id;
        float s = 0;
#pragma unroll
        for (int c = 0; c < 16; c++) s += p[(size_t)c * 1056];
        vk[bh * 1056 + id] = s;
    }
}

// =====================================================================
// M'[b][co][h*32+d] = sum_e w_proj[co][h*32+e] * vk[b*16+h][e][d]  (bf16 out)
// =====================================================================
__global__ __launch_bounds__(256)
void mprep(const float* __restrict__ Wproj, const float* __restrict__ vk,
           unsigned short* __restrict__ Mp)
{
    const int b   = blockIdx.y;
    const int co0 = blockIdx.x * 16;
    const int t   = threadIdx.x;
    for (int ci = 0; ci < 16; ci++) {
        int co = co0 + ci;
        for (int hd = t; hd < 512; hd += 256) {
            int h = hd >> 5, d = hd & 31;
            const float* wrow = Wproj + (size_t)co * 512 + h * 32;
            const float* vkb  = vk + (size_t)(b * 16 + h) * 1056 + d;
            float s = 0;
#pragma unroll
            for (int e = 0; e < 32; e++) s = fmaf(wrow[e], vkb[e * 32], s);
            Mp[((size_t)b * 256 + co) * 512 + hd] = f2b(s);
        }
    }
}

// =====================================================================
extern "C" void kernel_launch(void* const* d_in, const int* in_sizes, int n_in,
                              void* d_out, int out_size, void* d_ws, size_t ws_size,
                              hipStream_t stream)
{
    const float* x      = (const float*)d_in[0];
    const float* w_qkv  = (const float*)d_in[1];
    const float* w_dw   = (const float*)d_in[2];
    const float* w_pw   = (const float*)d_in[3];
    const float* w_proj = (const float*)d_in[4];
    const float* gamma  = (const float*)d_in[5];
    const float* beta   = (const float*)d_in[6];
    const float* rmean  = (const float*)d_in[7];
    const float* rvar   = (const float*)d_in[8];
    float* out = (float*)d_out;

    const size_t QB = (size_t)2 * QKV * Nsp;        // elements, 2-batch tensor
    unsigned short* qkv  = (unsigned short*)d_ws;   // bf16 [2][768][16384]
    unsigned short* agg2 = qkv + QB;                // bf16 [2][768][16384]
    unsigned short* Rb   = agg2 + QB;               // time-shared 50.3 MB region:
    unsigned short* xT   = Rb;                      //  [2][16384][256]  (steps 2-3)
    unsigned short* aggH = Rb;                      //  [2][768][16384]  (steps 4-5)
    unsigned short* qT   = Rb;                      //  [2][16384][512]  (steps 8-9)
    float* vkp  = (float*)(Rb + QB);                // 32*16*1056
    float* vkf  = vkp + (size_t)32 * 16 * 1056;     // 32*1056
    unsigned short* Mp  = (unsigned short*)(vkf + (size_t)32 * 1056); // 2*256*512
    unsigned short* wqb = Mp + (size_t)2 * 256 * 512;                 // 768*256

    dim3 blk(256);
    // 1) w_qkv -> bf16
    cvt_bf16<<<dim3(192), blk, 0, stream>>>(w_qkv, wqb, 768 * 256 / 4);
    // 2) xT = transpose(x) bf16
    transposeX<<<dim3(256, 4, 2), blk, 0, stream>>>(x, xT);
    // 3) qkv = wqb x xT  (MFMA, bf16 out, gload_lds staging)
    mfma_gemm<false, true><<<dim3(128, 6, 2), blk, 0, stream>>>(
        wqb, xT, qkv, 256, 768, 0, nullptr, nullptr, nullptr, nullptr);
    // 4) depthwise 5^3, both batches, pk-fp32 (R15 proven form; xT dead)
    dwconv5<<<dim3(768, 2), blk, 0, stream>>>(qkv, w_dw, aggH);
    // 5) grouped pointwise, both batches
    pwconv<<<dim3(64, 24, 2), blk, 0, stream>>>(aggH, w_pw, agg2);
    // 6) vk partials + reduce
    att_vk<<<dim3(16, 32), blk, 0, stream>>>(qkv, agg2, vkp);
    att_vk_reduce<<<dim3(32), blk, 0, stream>>>(vkp, vkf);
    // 7) M' (bf16)
    mprep<<<dim3(16, 2), blk, 0, stream>>>(w_proj, vkf, Mp);
    // 8) q~T with fused in-tile rden (aggH dead)
    transposeQT<<<dim3(256, 8, 2), blk, 0, stream>>>(qkv, agg2, vkf, qT);
    // 9) out = Mp x q~T + BN  (MFMA, f32 out, gload_lds staging)
    mfma_gemm<true, false><<<dim3(128, 2, 2), blk, 0, stream>>>(
        Mp, qT, out, 512, 256, (size_t)256 * 512,
        gamma, beta, rmean, rvar);
}